// Round 9
// baseline (240.541 us; speedup 1.0000x reference)
//
#include <hip/hip_runtime.h>
#include <hip/hip_bf16.h>
#include <math.h>

#define NROWS 8192
#define DDIM  128
#define JCHUNKS 16
#define JPER  (NROWS / JCHUNKS)        // 512 cols per chunk
#define STAGE_COLS 64
#define NSTAGES (JPER / STAGE_COLS)    // 8
#define ROWS_PER_BLOCK 256             // 4 waves x 64 rows
#define GRIDX (NROWS / ROWS_PER_BLOCK) // 32
#define NBUCK 1024

#define AS1 __attribute__((address_space(1)))
#define AS3 __attribute__((address_space(3)))

typedef __attribute__((ext_vector_type(8))) short bf16x8;  // 8 bf16 = 4 VGPRs
typedef __attribute__((ext_vector_type(4))) float f32x4;

// degree-4 poly for e^(c-1) on c in [-1.05, 1.05] (Chebyshev, abs err ~2e-4)
#define PB0 0.3678959f
#define PB1 0.3668905f
#define PB2 0.1836441f
#define PB3 0.0652423f
#define PB4 0.0161110f

__device__ inline f32x4 expcm1_4(f32x4 c) {   // ~ e^(c-1), 4-wide
  f32x4 e = {PB4, PB4, PB4, PB4};
  e = e * c + (f32x4){PB3, PB3, PB3, PB3};
  e = e * c + (f32x4){PB2, PB2, PB2, PB2};
  e = e * c + (f32x4){PB1, PB1, PB1, PB1};
  e = e * c + (f32x4){PB0, PB0, PB0, PB0};
  return e;
}

__device__ inline int bucket_of(float t) {
  int b = (int)((t + 1.0f) * (NBUCK / 2));
  return min(max(b, 0), NBUCK - 1);
}

// ---------------- kernel 0a: parallel histogram (grid 8 x 1024) ----------------
__global__ __launch_bounds__(1024) void hist_kernel(
    const float* __restrict__ targets, int* __restrict__ ghist) {
  __shared__ int h[NBUCK];
  const int tid = threadIdx.x;
  h[tid] = 0;
  __syncthreads();
  float t = targets[blockIdx.x * 1024 + tid];
  atomicAdd(&h[bucket_of(t)], 1);
  __syncthreads();
  int v = h[tid];
  if (v) atomicAdd(&ghist[tid], v);
}

// ---------------- kernel 0b: scan + scatter (1 x 1024) ----------------
// pi: sorted-pos -> original row; tps: t' = t + 10*sign(t) in sorted order
__global__ __launch_bounds__(1024) void scan_scatter_kernel(
    const float* __restrict__ targets, const int* __restrict__ ghist,
    int* __restrict__ pi, float* __restrict__ tps) {
  __shared__ int sc[NBUCK];
  __shared__ int cur[NBUCK];
  const int tid = threadIdx.x;
  int own = ghist[tid];
  sc[tid] = own;
  __syncthreads();
  for (int d = 1; d < NBUCK; d <<= 1) {   // Hillis-Steele inclusive scan
    int v = sc[tid];
    int add = (tid >= d) ? sc[tid - d] : 0;
    __syncthreads();
    sc[tid] = v + add;
    __syncthreads();
  }
  cur[tid] = sc[tid] - own;               // exclusive offsets as cursors
  __syncthreads();
  #pragma unroll
  for (int r = 0; r < NROWS / 1024; ++r) {
    int i = r * 1024 + tid;
    float t = targets[i];
    int pos = atomicAdd(&cur[bucket_of(t)], 1);
    pi[pos] = i;
    tps[pos] = t + (t > 0.0f ? 10.0f : -10.0f);
  }
}

// ---------------- kernel 1: gather-normalize into SORTED order ----------------
__global__ __launch_bounds__(256) void norm_kernel(
    const float* __restrict__ f1, const float* __restrict__ f2,
    const int* __restrict__ pi,
    __hip_bfloat16* __restrict__ f1b, __hip_bfloat16* __restrict__ f2b,
    float* __restrict__ out) {
  if (blockIdx.x == 0 && threadIdx.x == 0) out[0] = 0.0f;
  int t = threadIdx.x;
  int rloc = t >> 5;                 // 0..7
  int l = t & 31;
  int b = blockIdx.x;                // 0..2047
  int half = (b >= NROWS / 8) ? 1 : 0;
  int row = (b - half * (NROWS / 8)) * 8 + rloc;   // sorted position
  int srow = pi[row];                               // original row
  const float* src = half ? f2 : f1;
  __hip_bfloat16* dst = half ? f2b : f1b;

  float4 v = ((const float4*)src)[srow * (DDIM / 4) + l];
  float s = v.x * v.x + v.y * v.y + v.z * v.z + v.w * v.w;
  #pragma unroll
  for (int off = 1; off < 32; off <<= 1) s += __shfl_xor(s, off, 64);
  float inv = 1.0f / fmaxf(sqrtf(s), 1e-12f);
  __hip_bfloat16 hv[4];
  hv[0] = __float2bfloat16(v.x * inv);
  hv[1] = __float2bfloat16(v.y * inv);
  hv[2] = __float2bfloat16(v.z * inv);
  hv[3] = __float2bfloat16(v.w * inv);
  *(ushort4*)&dst[(size_t)row * DDIM + l * 4] = *(ushort4*)hv;
}

// ---------------- kernel 2: MFMA cos grid, 64 rows/wave, classified epilogue ----------------
// partials[(row*JCHUNKS + chunk)*4 + {Z, Zp, Cp, Np}], rows in sorted space
__global__ __launch_bounds__(256, 2) void stats_kernel(
    const __hip_bfloat16* __restrict__ f1b,
    const __hip_bfloat16* __restrict__ f2b,
    const float* __restrict__ tps,
    float* __restrict__ partials) {
  __shared__ __align__(16) char lds0[STAGE_COLS * 256];   // 16 KB
  __shared__ __align__(16) char lds1[STAGE_COLS * 256];   // 16 KB
  __shared__ __align__(16) float tsh[JPER];               // 2 KB (t', sorted chunk)

  const int chunk = blockIdx.y;
  const int i0 = blockIdx.x * ROWS_PER_BLOCK;
  const int w    = threadIdx.x >> 6;
  const int lane = threadIdx.x & 63;
  const int p15  = lane & 15;
  const int rl4  = lane >> 4;
  const int rbase = i0 + w * 64;                 // wave's 64 contiguous sorted rows

  // ---- A fragments resident for whole sweep: 4 rowsets x 4 k-steps ----
  bf16x8 afrag[4][4];
  #pragma unroll
  for (int rs = 0; rs < 4; ++rs) {
    const __hip_bfloat16* arow =
        &f1b[(size_t)(rbase + rs * 16 + p15) * DDIM + rl4 * 8];
    #pragma unroll
    for (int ks = 0; ks < 4; ++ks)
      afrag[rs][ks] = *(const bf16x8*)(arow + ks * 32);
  }

  // lane's C rows: component rs -> row rbase + rs*16 + rl4*4 + rr
  f32x4 tip4[4];
  #pragma unroll
  for (int rr = 0; rr < 4; ++rr)
    #pragma unroll
    for (int rs = 0; rs < 4; ++rs)
      tip4[rr][rs] = tps[rbase + rs * 16 + rl4 * 4 + rr];

  // sorted contiguous range: endpoints bound the wave's rows
  const float twmin = tps[rbase];
  const float twmax = tps[rbase + 63];

  f32x4 Z4[4]  = {};
  f32x4 Zp4[4] = {};
  f32x4 Cp4[4] = {};
  f32x4 Np4[4] = {};
  float posTiles = 0.0f;

  const int jb0 = chunk * JPER;

  // ---- DMA source offsets within a 64-row stage block (XOR chunk swizzle) ----
  int srcoff[4];
  #pragma unroll
  for (int q = 0; q < 4; ++q) {
    int rloc = w * 16 + q * 4 + rl4;
    int c    = p15 ^ (q * 4 + rl4);
    srcoff[q] = rloc * DDIM + c * 8;
  }

  // prologue: DMA t' chunk (2 rounds) + B stage 0 -> lds0
  #pragma unroll
  for (int rnd = 0; rnd < 2; ++rnd)
    __builtin_amdgcn_global_load_lds(
        (const AS1 void*)(tps + jb0 + rnd * 256 + w * 64 + lane),
        (AS3 void*)(&tsh[rnd * 256 + w * 64]), 4, 0, 0);
  {
    const __hip_bfloat16* gstage = f2b + (size_t)jb0 * DDIM;
    char* lbase = &lds0[w * 4096];
    #pragma unroll
    for (int q = 0; q < 4; ++q)
      __builtin_amdgcn_global_load_lds((const AS1 void*)(gstage + srcoff[q]),
                                       (AS3 void*)(lbase + q * 1024), 16, 0, 0);
  }

  for (int s = 0; s < NSTAGES; ++s) {
    __syncthreads();   // stage-s DMA complete; other buffer free

    if (s + 1 < NSTAGES) {
      const __hip_bfloat16* gstage = f2b + (size_t)(jb0 + (s + 1) * STAGE_COLS) * DDIM;
      char* lbase = ((s + 1) & 1) ? &lds1[w * 4096] : &lds0[w * 4096];
      #pragma unroll
      for (int q = 0; q < 4; ++q)
        __builtin_amdgcn_global_load_lds((const AS1 void*)(gstage + srcoff[q]),
                                         (AS3 void*)(lbase + q * 1024), 16, 0, 0);
    }

    const char* lb = (s & 1) ? lds1 : lds0;
    #pragma unroll
    for (int ct = 0; ct < 4; ++ct) {
      const int rloc = ct * 16 + p15;
      bf16x8 bfrag[4];
      #pragma unroll
      for (int ks = 0; ks < 4; ++ks)
        bfrag[ks] = *(const bf16x8*)(lb + rloc * 256 + (((rl4 + ks * 4) ^ p15) << 4));

      f32x4 acc[4] = {};
      #pragma unroll
      for (int ks = 0; ks < 4; ++ks)
        #pragma unroll
        for (int rs = 0; rs < 4; ++rs)
          acc[rs] = __builtin_amdgcn_mfma_f32_16x16x32_bf16(afrag[rs][ks], bfrag[ks], acc[rs], 0, 0, 0);

      // tile t' bounds from endpoints of the sorted 16-col group
      const int tb = s * STAGE_COLS + ct * 16;
      float jmn = tsh[tb], jmx = tsh[tb + 15];
      int uneg = __builtin_amdgcn_readfirstlane(
          ((jmn - twmax > 0.105f) || (twmin - jmx > 0.105f)) ? 1 : 0);
      int upos = __builtin_amdgcn_readfirstlane(
          ((twmax - jmn <= 0.095f) && (jmx - twmin <= 0.095f)) ? 1 : 0);

      if (uneg) {
        #pragma unroll
        for (int rr = 0; rr < 4; ++rr) {
          f32x4 c4 = {acc[0][rr], acc[1][rr], acc[2][rr], acc[3][rr]};
          Z4[rr] += expcm1_4(c4);
        }
      } else if (upos) {
        posTiles += 1.0f;
        #pragma unroll
        for (int rr = 0; rr < 4; ++rr) {
          f32x4 c4 = {acc[0][rr], acc[1][rr], acc[2][rr], acc[3][rr]};
          f32x4 e4 = expcm1_4(c4);
          Z4[rr]  += e4;
          Zp4[rr] += e4;
          Cp4[rr] += c4;
        }
      } else {
        float tj = tsh[tb + p15];
        #pragma unroll
        for (int rr = 0; rr < 4; ++rr) {
          f32x4 c4 = {acc[0][rr], acc[1][rr], acc[2][rr], acc[3][rr]};
          f32x4 e4 = expcm1_4(c4);
          f32x4 m4;
          #pragma unroll
          for (int rs = 0; rs < 4; ++rs)
            m4[rs] = (__builtin_fabsf(tip4[rr][rs] - tj) <= 0.1f) ? 1.0f : 0.0f;
          Z4[rr]  += e4;
          Zp4[rr] += m4 * e4;
          Cp4[rr] += m4 * c4;
          Np4[rr] += m4;
        }
      }
    }
  }

  // uniform-pos tiles: every lane's column hit all its rows
  #pragma unroll
  for (int rr = 0; rr < 4; ++rr)
    Np4[rr] += (f32x4){posTiles, posTiles, posTiles, posTiles};

  // reduce over the 16 lanes (p15) sharing each row
  #pragma unroll
  for (int rr = 0; rr < 4; ++rr) {
    for (int off = 1; off < 16; off <<= 1) {
      #pragma unroll
      for (int rs = 0; rs < 4; ++rs) {
        Z4[rr][rs]  += __shfl_xor(Z4[rr][rs],  off, 64);
        Zp4[rr][rs] += __shfl_xor(Zp4[rr][rs], off, 64);
        Cp4[rr][rs] += __shfl_xor(Cp4[rr][rs], off, 64);
        Np4[rr][rs] += __shfl_xor(Np4[rr][rs], off, 64);
      }
    }
  }
  if (p15 == 0) {
    #pragma unroll
    for (int rs = 0; rs < 4; ++rs)
      #pragma unroll
      for (int rr = 0; rr < 4; ++rr) {
        size_t row = rbase + rs * 16 + rl4 * 4 + rr;
        f32x4 st = {Z4[rr][rs], Zp4[rr][rs], Cp4[rr][rs], Np4[rr][rs]};
        *(f32x4*)&partials[((size_t)row * JCHUNKS + chunk) * 4] = st;
      }
  }
}

// ---------------- kernel 3: per-row loss + global mean (atomic) ----------------
__global__ void finalize_rows(const float* __restrict__ partials,
                              float* __restrict__ out) {
  int r = blockIdx.x * 256 + threadIdx.x;   // grid 32 x 256
  float Z = 0, Zp = 0, Cp = 0, Np = 0;
  for (int ch = 0; ch < JCHUNKS; ++ch) {
    float4 p = *(const float4*)&partials[((size_t)r * JCHUNKS + ch) * 4];
    Z += p.x; Zp += p.y; Cp += p.z; Np += p.w;
  }
  float Zn = Z - Zp;
  float nn = (float)NROWS - Np;
  float spos = (1.0f + logf(Z)) - Cp / Np;
  float sneg = Zn / Z - nn * 1e-10f;
  float per_row = spos + sneg / nn;

  float v = per_row;
  for (int off = 32; off; off >>= 1) v += __shfl_xor(v, off, 64);
  __shared__ float wsum[4];
  int lane = threadIdx.x & 63, wid = threadIdx.x >> 6;
  if (lane == 0) wsum[wid] = v;
  __syncthreads();
  if (threadIdx.x == 0)
    atomicAdd(out, (wsum[0] + wsum[1] + wsum[2] + wsum[3]) * (1.0f / (float)NROWS));
}

// ---------------- launch ----------------
extern "C" void kernel_launch(void* const* d_in, const int* in_sizes, int n_in,
                              void* d_out, int out_size, void* d_ws, size_t ws_size,
                              hipStream_t stream) {
  const float* f1  = (const float*)d_in[0];
  const float* f2  = (const float*)d_in[1];
  const float* tgt = (const float*)d_in[2];
  float* out = (float*)d_out;

  char* ws = (char*)d_ws;
  __hip_bfloat16* f1b = (__hip_bfloat16*)ws;                          // 2 MB
  __hip_bfloat16* f2b = (__hip_bfloat16*)(ws + (size_t)NROWS * DDIM * 2);
  float* partials = (float*)(ws + (size_t)NROWS * DDIM * 4);          // 2 MB
  int*   pi    = (int*)((char*)partials + (size_t)NROWS * JCHUNKS * 16);
  float* tps   = (float*)((char*)pi + NROWS * 4);
  int*   ghist = (int*)((char*)tps + NROWS * 4);

  hipMemsetAsync(ghist, 0, NBUCK * sizeof(int), stream);
  hist_kernel<<<NROWS / 1024, 1024, 0, stream>>>(tgt, ghist);
  scan_scatter_kernel<<<1, 1024, 0, stream>>>(tgt, ghist, pi, tps);
  norm_kernel<<<2 * (NROWS / 8), 256, 0, stream>>>(f1, f2, pi, f1b, f2b, out);
  dim3 g2(GRIDX, JCHUNKS);
  stats_kernel<<<g2, 256, 0, stream>>>(f1b, f2b, tps, partials);
  finalize_rows<<<NROWS / 256, 256, 0, stream>>>(partials, out);
}